// Round 11
// baseline (164.796 us; speedup 1.0000x reference)
//
#include <hip/hip_runtime.h>
#include <math.h>

// Problem: [16,1,1024,1024] fp32 pred/target -> scalar weighted mean-abs curvature loss.
// R18: cross-lane tap sharing. Evidence ledger:
//  R7/R15 (56us main, VALUBusy 62%, VGPR 64): best. dur_us = main + ~96us fixed.
//  R8 (70us) manual pipeline | R11 (373us) per-block fence poison | R12 (91us)
//  coarse grid+VGPR144 | R14 (103us) overlapping dwordx4 TA-split | R16 (109us)
//  LDS stage-all barrier drain | R17 (69us) ROWS=32: compiler took VGPR 112,
//  occ 18.5%, FETCH UP 103MB (vertical-halo locality worsened). R7 shape is a
//  local optimum in schedule/sync/coarsening/width/staging/height.
// R18 change: each column was loaded 3x by adjacent lanes (6 VMEM/row). Now
// each lane loads only its CENTER column (2 VMEM/row); w0/w2 come from
// __shfl_up/__shfl_down (4x ds_bpermute, LDS pipe -- no VALU/VMEM slots).
// Wave-boundary halo via overlapped tiling: 64-lane wave covers 62 output
// cols + 2 halo-only lanes (outputs masked by per-thread weights, computed
// once). TILES_X=5 (248 cols/block), NBLOCKS=5120; fully-invalid waves take a
// wave-uniform __ballot early-out (+6% lane overhead net). Edge zeros fold
// into 2 cndmasks on the center load and propagate through the shuffles.
// Evades all 6 failure modes: fewer latency events (6->2/row), 3x deeper
// effective lookahead at SAME VGPR, no wide loads, no barriers, no fences,
// finer grid. Numerics: identical per-pixel values+op order; only wave-sum
// grouping shifts (absmax ~1e-6 << 2.8e-3).
// Workspace: 5120 floats (20.5KB); R7-geometry fallback if ws too small.

constexpr int IMG_B = 16;
constexpr int IMG_H = 1024;
constexpr int IMG_W = 1024;
constexpr int ROWS  = 16;                      // rows per block
constexpr int BLOCK = 256;                     // 4 waves
constexpr int WCOLS = 62;                      // output cols per wave
constexpr int TCOLS = WCOLS * 4;               // 248 output cols per block
constexpr int TILES_X = (IMG_W + TCOLS - 1) / TCOLS;   // 5
constexpr int TILES_Y = IMG_H / ROWS;          // 64
constexpr int NBLOCKS = IMG_B * TILES_Y * TILES_X;     // 5120
// R7 fallback geometry
constexpr int TILES_X7 = IMG_W / BLOCK;        // 4
constexpr int NBLOCKS7 = IMG_B * TILES_Y * TILES_X7;   // 4096
constexpr float EPS = 1e-8f;

// scale constants: p = gx/80, q = gy/80, r = rxx/300, 2s = sxy/200, t = tyy/300
constexpr float A2 = 1.0f / 6400.0f;
constexpr float Bc = 1.0f / 300.0f;
constexpr float C2 = 1.0f / 200.0f;

typedef float f2v __attribute__((ext_vector_type(2)));

__device__ __forceinline__ f2v pk_fma(f2v a, f2v b, f2v c) {
    return __builtin_elementwise_fma(a, b, c);
}

// rolling-window row state, lanes = {pred, target}
struct Rowv { f2v hx, hs, rs; };

// prof/plan true scale; mean2 = 2*mean (weight absorbs the 1/2). Lane-parallel
// over {pred, target}; transcendentals + flat-mask stay per-component.
__device__ __forceinline__ void curv_pair(const Rowv& a, const Rowv& b, const Rowv& c,
                                          f2v& prof, f2v& plan, f2v& mean2)
{
    const f2v A2f = {A2, A2}, Bcf = {Bc, Bc}, C2f = {C2, C2};
    const f2v m3  = {-3.0f, -3.0f}, two = {2.0f, 2.0f};
    const f2v epsf = {EPS, EPS};

    const f2v gx  = pk_fma(two, b.hx, a.hx + c.hx);   // sobel_x (raw)
    const f2v gy  = c.hs - a.hs;                      // sobel_y (raw)
    const f2v tot = (a.rs + c.rs) + b.rs;             // 3x3 sum
    const f2v H   = (a.hs + c.hs) + b.hs;
    const f2v rxx = pk_fma(m3, H - tot, tot);         // k_xx * 3 (raw)
    const f2v tyy = pk_fma(m3, b.rs, tot);            // k_yy * 3 (raw)
    const f2v sxy = a.hx - c.hx;                      // k_xy * 4 (raw)

    const f2v gx2 = gx * gx, gy2 = gy * gy, gxgy = gx * gy;
    const f2v g2  = gx2 + gy2;
    const f2v d1  = A2f * g2;                         // p^2 + q^2
    const f2v od  = d1 + f2v{1.0f, 1.0f};

    f2v rsq_od, sq_d1;                                // per-component transcendentals
    rsq_od.x = __builtin_amdgcn_rsqf(od.x);
    rsq_od.y = __builtin_amdgcn_rsqf(od.y);
    sq_d1.x  = __builtin_amdgcn_sqrtf(d1.x);
    sq_d1.y  = __builtin_amdgcn_sqrtf(d1.y);
    const f2v sq_od = od * rsq_od;                    // sqrt(1+d1)

    const f2v h1    = pk_fma(tyy, gy2, rxx * gx2);
    const f2v h3    = pk_fma(tyy, gx2, rxx * gy2);
    const f2v h2c   = C2f * (sxy * gxgy);
    const f2v nprof = A2f * pk_fma(Bcf, h1,  h2c);    // r*p2+2s*pq+t*q2
    const f2v nplan = A2f * pk_fma(Bcf, h3, -h2c);    // r*q2-2s*pq+t*p2
    const f2v mnum  = pk_fma(Bcf, rxx + tyy, nplan);  // (1+q2)r-2pq*s+(1+p2)t

    const f2v den_p = pk_fma(d1, sq_od, epsf);        // d1*sqrt(1+d1)+EPS
    const f2v den_l = pk_fma(d1, sq_d1, epsf);        // d1^1.5+EPS
    const f2v plprod = den_p * den_l;                 // >=1e-16, no underflow
    f2v rcpPL;
    rcpPL.x = __builtin_amdgcn_rcpf(plprod.x);
    rcpPL.y = __builtin_amdgcn_rcpf(plprod.y);

    prof  = (nprof * den_l) * rcpPL;
    plan  = (nplan * den_p) * rcpPL;
    mean2 = mnum * ((rsq_od * rsq_od) * rsq_od);      // mnum/od^1.5 = 2*mean
    // flat mask per component
    prof.x = (d1.x < EPS) ? 0.0f : prof.x;
    prof.y = (d1.y < EPS) ? 0.0f : prof.y;
    plan.x = (d1.x < EPS) ? 0.0f : plan.x;
    plan.y = (d1.y < EPS) ? 0.0f : plan.y;
}

// ---------------- R18: shfl-halo main kernel ----------------
__global__ __launch_bounds__(BLOCK) void curv_loss_main_shfl(
    const float* __restrict__ pred, const float* __restrict__ targ,
    float* __restrict__ blocksums)
{
    const int tid = threadIdx.x;
    const int b   = blockIdx.x;
    const int tx  = b % TILES_X;              // 5-way: compiler magic-div
    const int r2  = b / TILES_X;
    const int ty  = r2 & (TILES_Y - 1);
    const int img = r2 >> 6;
    const int y0  = ty * ROWS;
    const int wv  = tid >> 6, l = tid & 63;
    // this lane's CENTER column (lane 0 = left halo, lane 63 = right halo)
    const int cl  = tx * TCOLS + wv * WCOLS + l - 1;
    const bool validC = (unsigned)cl < (unsigned)IMG_W;
    const int  eC = (validC ? cl : (cl < 0 ? 0 : IMG_W - 1)) << 2;   // clamped
    // output validity -> fold into the loss weights (computed once, no per-iter cost)
    const bool outv = (l >= 1) && (l <= WCOLS) && validC;
    const float W05 = outv ? 0.5f : 0.0f;
    const float W03 = outv ? 0.3f : 0.0f;
    const float W01 = outv ? 0.1f : 0.0f;

    const size_t ibase = (size_t)img * (size_t)(IMG_H * IMG_W);
    const char* __restrict__ Pc = (const char*)(pred + ibase);
    const char* __restrict__ Tc = (const char*)(targ + ibase);

    float acc = 0.0f;
    if (__ballot(outv) != 0ULL) {             // wave-uniform early-out (tile-4 idle waves)
        // prep one row: 2 center loads + 4 shuffles; image-edge zeros come from
        // the masked center load and propagate through the shuffles.
        auto prep = [&](int y, Rowv& o) {
            if ((unsigned)y < (unsigned)IMG_H) {      // block-uniform branch
                const int vo = y << 12;
                float pc = *(const float*)(Pc + vo + eC);
                float tc = *(const float*)(Tc + vo + eC);
                pc = validC ? pc : 0.0f;
                tc = validC ? tc : 0.0f;
                const float p0 = __shfl_up(pc, 1u, 64);
                const float t0 = __shfl_up(tc, 1u, 64);
                const float p2 = __shfl_down(pc, 1u, 64);
                const float t2 = __shfl_down(tc, 1u, 64);
                const f2v w0 = {p0, t0};              // col cl-1
                const f2v w1 = {pc, tc};              // col cl
                const f2v w2 = {p2, t2};              // col cl+1
                const f2v e = w0 + w2;
                o.hx = w2 - w0;
                o.hs = pk_fma(f2v{2.0f, 2.0f}, w1, e);
                o.rs = e + w1;
            } else {                                   // zero 'SAME' padding row
                o.hx = f2v{0.0f, 0.0f}; o.hs = f2v{0.0f, 0.0f}; o.rs = f2v{0.0f, 0.0f};
            }
        };

        Rowv w[3];
        prep(y0 - 1, w[0]);
        prep(y0,     w[1]);

#pragma unroll
        for (int i = 0; i < ROWS; ++i) {
            const int ia = i % 3, ib = (i + 1) % 3, ic = (i + 2) % 3;
            prep(y0 + i + 1, w[ic]);
            f2v prof, plan, mean2;
            curv_pair(w[ia], w[ib], w[ic], prof, plan, mean2);
            acc = fmaf(W05, fabsf(prof.x  - prof.y),  acc);
            acc = fmaf(W03, fabsf(plan.x  - plan.y),  acc);
            acc = fmaf(W01, fabsf(mean2.x - mean2.y), acc);  // 0.2*|dMean|
        }
    }

    // wave64 reduce, then cross-wave via LDS
#pragma unroll
    for (int off = 32; off > 0; off >>= 1) acc += __shfl_down(acc, off, 64);
    __shared__ float ws[BLOCK / 64];
    const int lane = tid & 63, wid = tid >> 6;
    if (lane == 0) ws[wid] = acc;
    __syncthreads();
    if (tid == 0)
        blocksums[b] = (ws[0] + ws[1]) + (ws[2] + ws[3]);
}

// ---------------- R7 fallback main kernel (proven 56us) ----------------
__global__ __launch_bounds__(BLOCK) void curv_loss_main_r7(
    const float* __restrict__ pred, const float* __restrict__ targ,
    float* __restrict__ blocksums)
{
    const int tid = threadIdx.x;
    const int b   = blockIdx.x;
    const int tx  = b & (TILES_X7 - 1);
    const int ty  = (b >> 2) & (TILES_Y - 1);
    const int img = b >> 8;
    const int y0  = ty * ROWS;
    const int x   = tx * BLOCK + tid;

    const size_t ibase = (size_t)img * (size_t)(IMG_H * IMG_W);
    const char* __restrict__ Pc = (const char*)(pred + ibase);
    const char* __restrict__ Tc = (const char*)(targ + ibase);

    const bool xm = (x > 0);
    const bool xp = (x < IMG_W - 1);
    const int eL = (x + (xm ? -1 : 0)) << 2;
    const int eC = x << 2;
    const int eR = (x + (xp ? +1 : 0)) << 2;

    auto prep = [&](int y, Rowv& o) {
        if ((unsigned)y < (unsigned)IMG_H) {
            const int vo = y << 12;
            const float pl = *(const float*)(Pc + vo + eL);
            const float tl = *(const float*)(Tc + vo + eL);
            const float pc = *(const float*)(Pc + vo + eC);
            const float tc = *(const float*)(Tc + vo + eC);
            const float pr = *(const float*)(Pc + vo + eR);
            const float tr = *(const float*)(Tc + vo + eR);
            const f2v w0 = {xm ? pl : 0.0f, xm ? tl : 0.0f};
            const f2v w1 = {pc, tc};
            const f2v w2 = {xp ? pr : 0.0f, xp ? tr : 0.0f};
            const f2v e = w0 + w2;
            o.hx = w2 - w0;
            o.hs = pk_fma(f2v{2.0f, 2.0f}, w1, e);
            o.rs = e + w1;
        } else {
            o.hx = f2v{0.0f, 0.0f}; o.hs = f2v{0.0f, 0.0f}; o.rs = f2v{0.0f, 0.0f};
        }
    };

    Rowv w[3];
    prep(y0 - 1, w[0]);
    prep(y0,     w[1]);

    float acc = 0.0f;
#pragma unroll
    for (int i = 0; i < ROWS; ++i) {
        const int ia = i % 3, ib = (i + 1) % 3, ic = (i + 2) % 3;
        prep(y0 + i + 1, w[ic]);
        f2v prof, plan, mean2;
        curv_pair(w[ia], w[ib], w[ic], prof, plan, mean2);
        acc = fmaf(0.5f, fabsf(prof.x  - prof.y),  acc);
        acc = fmaf(0.3f, fabsf(plan.x  - plan.y),  acc);
        acc = fmaf(0.1f, fabsf(mean2.x - mean2.y), acc);
    }

#pragma unroll
    for (int off = 32; off > 0; off >>= 1) acc += __shfl_down(acc, off, 64);
    __shared__ float ws[BLOCK / 64];
    const int lane = tid & 63, wid = tid >> 6;
    if (lane == 0) ws[wid] = acc;
    __syncthreads();
    if (tid == 0)
        blocksums[b] = (ws[0] + ws[1]) + (ws[2] + ws[3]);
}

__global__ __launch_bounds__(BLOCK) void curv_loss_final(
    const float* __restrict__ blocksums, int n, float* __restrict__ out)
{
    const int tid = threadIdx.x;
    float v = 0.0f;
    for (int i = tid; i < n; i += BLOCK) v += blocksums[i];
#pragma unroll
    for (int off = 32; off > 0; off >>= 1) v += __shfl_down(v, off, 64);
    __shared__ float ws[BLOCK / 64];
    const int lane = tid & 63, wid = tid >> 6;
    if (lane == 0) ws[wid] = v;
    __syncthreads();
    if (tid == 0) {
        const float tot = (ws[0] + ws[1]) + (ws[2] + ws[3]);
        out[0] = tot * (1.0f / (float)(IMG_B * IMG_H * IMG_W));
    }
}

extern "C" void kernel_launch(void* const* d_in, const int* in_sizes, int n_in,
                              void* d_out, int out_size, void* d_ws, size_t ws_size,
                              hipStream_t stream)
{
    const float* pred = (const float*)d_in[0];
    const float* targ = (const float*)d_in[1];
    float* out = (float*)d_out;
    float* blocksums = (float*)d_ws;

    if (ws_size >= (size_t)NBLOCKS * sizeof(float)) {
        curv_loss_main_shfl<<<NBLOCKS, BLOCK, 0, stream>>>(pred, targ, blocksums);
        curv_loss_final<<<1, BLOCK, 0, stream>>>(blocksums, NBLOCKS, out);
    } else {
        curv_loss_main_r7<<<NBLOCKS7, BLOCK, 0, stream>>>(pred, targ, blocksums);
        curv_loss_final<<<1, BLOCK, 0, stream>>>(blocksums, NBLOCKS7, out);
    }
}